// Round 12
// baseline (560.293 us; speedup 1.0000x reference)
//
#include <hip/hip_runtime.h>
#include <hip/hip_bf16.h>

// BiAttention: B=16, L=M=2048, D=1024.
//  conv_in -> conv_mem(fused Kh+Vt transpose) -> gemm1 -> softmax_rows
//  -> w2a(+o2 zero) -> o2 -> gemm2(fused epilogue)
// R12 = R8 core (proven 551us: m97 128^2 2-barrier GEMMs, 16x16x32 MFMA,
// (256,4), GL16, xor swizzle, LDS-staged vectorized epilogues) with:
//  - inH reverted (R11 neutral, worse absmax)
//  - tr fused into conv_mem (saves 67MB Kh re-read + a launch)
//  - o2 split 4x finer (256 -> 1024 blocks; was 1 block/CU latency-bound)
// Closed lanes: 8-phase (R3/R4/R9), 32x32 MFMA (R10 conflict-period), fp8 P.

#define BDIM 16
#define LDIM 2048
#define MDIM 2048
#define DDIM 1024
#define NEGF (-60000.0f)

typedef float    f32x4v __attribute__((ext_vector_type(4)));
typedef _Float16 half8  __attribute__((ext_vector_type(8)));
typedef _Float16 half4  __attribute__((ext_vector_type(4)));

#define GL16(gp, lp)                                                        \
  __builtin_amdgcn_global_load_lds(                                         \
      (const __attribute__((address_space(1))) unsigned int*)(gp),          \
      (__attribute__((address_space(3))) unsigned int*)(lp), 16, 0, 0)

__device__ __forceinline__ float4 m4(const float4 a, const float4 b) {
  return (float4){a.x * b.x, a.y * b.y, a.z * b.z, a.w * b.w};
}
__device__ __forceinline__ void nts4(const float4 v, float* p) {
  f32x4v w = {v.x, v.y, v.z, v.w};
  __builtin_nontemporal_store(w, (f32x4v*)p);
}

// ---------------- input side: Qh + idot ----------------
__global__ __launch_bounds__(256) void conv_in(
    const float* __restrict__ input, const float* __restrict__ w_in,
    const float* __restrict__ scale, _Float16* __restrict__ Qh,
    float* __restrict__ idot) {
  const int t = threadIdx.x, lane = t & 63, wid = t >> 6;
  const size_t row = (size_t)blockIdx.x * 4 + wid;
  const float* ir = input + row * DDIM;
  float di = 0.f;
#pragma unroll
  for (int c = 0; c < 4; ++c) {
    const int off = c * 256 + lane * 4;
    float4 sc4 = *(const float4*)&scale[off];
    float4 wi4 = *(const float4*)&w_in[off];
    float4 v = *(const float4*)&ir[off];
    di += v.x * wi4.x + v.y * wi4.y + v.z * wi4.z + v.w * wi4.w;
    half4 q = { (_Float16)(v.x * sc4.x), (_Float16)(v.y * sc4.y),
                (_Float16)(v.z * sc4.z), (_Float16)(v.w * sc4.w) };
    *(half4*)&Qh[row * DDIM + off] = q;
  }
#pragma unroll
  for (int o = 1; o < 64; o <<= 1) di += __shfl_xor(di, o, 64);
  if (lane == 0) idot[row] = di;
}

// ---------------- memory side: Kh + Vt (fused transpose) + mdot ----------------
__global__ __launch_bounds__(256) void conv_mem(
    const float* __restrict__ memory, const float* __restrict__ w_mem,
    _Float16* __restrict__ Kh, _Float16* __restrict__ Vt,
    float* __restrict__ mdot) {
  const int b = blockIdx.y, m0 = blockIdx.x * 64;
  const int t = threadIdx.x;
  const int r = t >> 2, cs = (t & 3) * 16;   // row 0..63, col-chunk of 16
  __shared__ _Float16 sT[64][66];            // stride 66: 2-way banks (free)
  float dm = 0.f;
  for (int ch = 0; ch < 16; ++ch) {
    const int d0 = ch * 64;
    const float* src = memory + ((size_t)b * MDIM + m0 + r) * DDIM + d0 + cs;
    float4 v0 = *(const float4*)&src[0];
    float4 v1 = *(const float4*)&src[4];
    float4 v2 = *(const float4*)&src[8];
    float4 v3 = *(const float4*)&src[12];
    const float* wm = &w_mem[d0 + cs];
    float4 w0 = *(const float4*)&wm[0];
    float4 w1 = *(const float4*)&wm[4];
    float4 w2v = *(const float4*)&wm[8];
    float4 w3 = *(const float4*)&wm[12];
    dm += v0.x * w0.x + v0.y * w0.y + v0.z * w0.z + v0.w * w0.w
        + v1.x * w1.x + v1.y * w1.y + v1.z * w1.z + v1.w * w1.w
        + v2.x * w2v.x + v2.y * w2v.y + v2.z * w2v.z + v2.w * w2v.w
        + v3.x * w3.x + v3.y * w3.y + v3.z * w3.z + v3.w * w3.w;
    half8 h0 = { (_Float16)v0.x, (_Float16)v0.y, (_Float16)v0.z, (_Float16)v0.w,
                 (_Float16)v1.x, (_Float16)v1.y, (_Float16)v1.z, (_Float16)v1.w };
    half8 h1 = { (_Float16)v2.x, (_Float16)v2.y, (_Float16)v2.z, (_Float16)v2.w,
                 (_Float16)v3.x, (_Float16)v3.y, (_Float16)v3.z, (_Float16)v3.w };
    _Float16* kp = &Kh[((size_t)b * MDIM + m0 + r) * DDIM + d0 + cs];
    *(half8*)&kp[0] = h0;
    *(half8*)&kp[8] = h1;
    *(half8*)&sT[r][cs]     = h0;
    *(half8*)&sT[r][cs + 8] = h1;
    __syncthreads();
    {
      const int dr = r, ms = cs;             // reuse decomposition
      union { _Float16 h[16]; half8 v[2]; } tmp;
#pragma unroll
      for (int j = 0; j < 16; ++j) tmp.h[j] = sT[ms + j][dr];
      _Float16* dst = Vt + ((size_t)b * DDIM + d0 + dr) * MDIM + m0 + ms;
      *(half8*)&dst[0] = tmp.v[0];
      *(half8*)&dst[8] = tmp.v[1];
    }
    __syncthreads();
  }
  dm += __shfl_xor(dm, 1);
  dm += __shfl_xor(dm, 2);
  if ((t & 3) == 0) mdot[(size_t)b * MDIM + m0 + r] = dm;
}

// ============ m97-style 128^2 GEMM core (R5/R8, proven) ============
__device__ __forceinline__ void stage128(const _Float16* __restrict__ Ab,
                                         const _Float16* __restrict__ Bb,
                                         _Float16* sAb, _Float16* sBb,
                                         int stride, int k0, int wid, int lane) {
  const int rsub = lane >> 3;
  const int sc = ((lane & 7) ^ rsub) * 8;
#pragma unroll
  for (int j = 0; j < 4; ++j) {
    const int r0 = wid * 32 + j * 8;
    const size_t go = (size_t)(r0 + rsub) * stride + k0 + sc;
    GL16(Ab + go, sAb + r0 * 64);
    GL16(Bb + go, sBb + r0 * 64);
  }
}

__device__ __forceinline__ void compute128(const _Float16* sAb, const _Float16* sBb,
                                           f32x4v acc[4][4], int wr, int wc,
                                           int lane) {
  const int l15 = lane & 15;
#pragma unroll
  for (int kk = 0; kk < 2; ++kk) {
    const int colh = ((kk * 4 + (lane >> 4)) ^ (lane & 7)) * 8;
    half8 aF[4], bF[4];
#pragma unroll
    for (int i = 0; i < 4; ++i) {
      aF[i] = *(const half8*)&sAb[(wr * 64 + i * 16 + l15) * 64 + colh];
      bF[i] = *(const half8*)&sBb[(wc * 64 + i * 16 + l15) * 64 + colh];
    }
#pragma unroll
    for (int mi = 0; mi < 4; ++mi)
#pragma unroll
      for (int ni = 0; ni < 4; ++ni)
        acc[mi][ni] = __builtin_amdgcn_mfma_f32_16x16x32_f16(aF[mi], bF[ni],
                                                             acc[mi][ni], 0, 0, 0);
  }
}

// ---------------- GEMM1: S = Q @ K^T + dots, masked ----------------
__global__ __launch_bounds__(256, 4) void gemm1_kernel(
    const _Float16* __restrict__ Qh, const _Float16* __restrict__ Kh,
    const float* __restrict__ idot, const float* __restrict__ mdot,
    const int* __restrict__ mask, _Float16* __restrict__ Sp) {
  const int id = blockIdx.x;                  // nwg = 4096
  const int wg = (id & 7) * 512 + (id >> 3);
  const int b = wg >> 8, rem = wg & 255, by = rem >> 4, bx = rem & 15;
  const int t = threadIdx.x, lane = t & 63, wid = t >> 6;
  const int wr = wid >> 1, wc = wid & 1;
  __shared__ union SM1 {
    struct { _Float16 a[128 * 64]; _Float16 b[128 * 64]; } ab;
    _Float16 s[128 * 140];                     // padded S-tile stage
  } sm;
  __shared__ float s_dl[128], s_dm[128];
  __shared__ int   s_ml[128], s_mm[128];
  if (t < 128) {
    s_dl[t] = idot[b * LDIM + by * 128 + t];
    s_ml[t] = mask[b * LDIM + by * 128 + t];
    s_dm[t] = mdot[b * MDIM + bx * 128 + t];
    s_mm[t] = mask[b * MDIM + bx * 128 + t];
  }
  const _Float16* Ab = Qh + ((size_t)b * LDIM + by * 128) * DDIM;
  const _Float16* Bb = Kh + ((size_t)b * MDIM + bx * 128) * DDIM;
  f32x4v acc[4][4];
#pragma unroll
  for (int i = 0; i < 4; ++i)
#pragma unroll
    for (int j = 0; j < 4; ++j) acc[i][j] = (f32x4v){0.f, 0.f, 0.f, 0.f};

  for (int ks = 0; ks < DDIM / 64; ++ks) {
    __syncthreads();
    stage128(Ab, Bb, sm.ab.a, sm.ab.b, DDIM, ks * 64, wid, lane);
    __syncthreads();
    compute128(sm.ab.a, sm.ab.b, acc, wr, wc, lane);
  }

  // epilogue: stage f16 S-tile in LDS, then half8 row writes
  __syncthreads();
  const int rb = wr * 64, cb = wc * 64;
#pragma unroll
  for (int mi = 0; mi < 4; ++mi)
#pragma unroll
    for (int ni = 0; ni < 4; ++ni)
#pragma unroll
      for (int r = 0; r < 4; ++r) {
        const int lrow = rb + mi * 16 + (lane >> 4) * 4 + r;
        const int lcol = cb + ni * 16 + (lane & 15);
        float s = acc[mi][ni][r] + s_dl[lrow] + s_dm[lcol];
        if ((s_ml[lrow] | s_mm[lcol]) != 0) s = NEGF;
        sm.s[lrow * 140 + lcol] = (_Float16)s;
      }
  __syncthreads();
  const int r16 = t >> 4, c8 = (t & 15) * 8;
#pragma unroll
  for (int rd = 0; rd < 8; ++rd) {
    const int lrow = rd * 16 + r16;
    half8 v = *(const half8*)&sm.s[lrow * 140 + c8];
    *(half8*)&Sp[((size_t)b * LDIM + by * 128 + lrow) * MDIM + bx * 128 + c8] = v;
  }
}

// ---------------- per-row softmax (in place) + rowmax ----------------
__global__ __launch_bounds__(256) void softmax_rows(_Float16* __restrict__ Sp,
                                                    float* __restrict__ rmax) {
  const int t = threadIdx.x, lane = t & 63, wid = t >> 6;
  const size_t row = (size_t)blockIdx.x * 4 + wid;
  _Float16* rp = Sp + row * (size_t)MDIM;
  float s[32];
#pragma unroll
  for (int c = 0; c < 4; ++c) {
    half8 v = *(const half8*)&rp[c * 512 + lane * 8];
#pragma unroll
    for (int j = 0; j < 8; ++j) s[c * 8 + j] = (float)v[j];
  }
  float m = -3.0e38f;
#pragma unroll
  for (int i = 0; i < 32; ++i) m = fmaxf(m, s[i]);
#pragma unroll
  for (int o = 1; o < 64; o <<= 1) m = fmaxf(m, __shfl_xor(m, o, 64));
  float sum = 0.f;
#pragma unroll
  for (int i = 0; i < 32; ++i) { s[i] = __expf(s[i] - m); sum += s[i]; }
#pragma unroll
  for (int o = 1; o < 64; o <<= 1) sum += __shfl_xor(sum, o, 64);
  const float inv = 1.f / sum;
#pragma unroll
  for (int c = 0; c < 4; ++c) {
    half8 v;
#pragma unroll
    for (int j = 0; j < 8; ++j) v[j] = (_Float16)(s[c * 8 + j] * inv);
    *(half8*)&rp[c * 512 + lane * 8] = v;
  }
  if (lane == 0) rmax[row] = m;
}

// ---------------- w2 = softmax_l(rowmax) per batch (+ zero o2) ----------------
__global__ __launch_bounds__(256) void w2a_kernel(const float* __restrict__ rmax,
                                                  float* __restrict__ w2,
                                                  float* __restrict__ o2) {
  const int b = blockIdx.x, t = threadIdx.x;
  ((float4*)(o2 + (size_t)b * DDIM))[t] = (float4){0.f, 0.f, 0.f, 0.f};
  __shared__ float red[256];
  const float* rm = rmax + (size_t)b * LDIM;
  float vals[8]; float lm = -3.0e38f;
#pragma unroll
  for (int j = 0; j < 8; ++j) { vals[j] = rm[t + j * 256]; lm = fmaxf(lm, vals[j]); }
  red[t] = lm; __syncthreads();
  for (int s = 128; s > 0; s >>= 1) {
    if (t < s) red[t] = fmaxf(red[t], red[t + s]);
    __syncthreads();
  }
  const float M = red[0]; __syncthreads();
  float ls = 0.f;
#pragma unroll
  for (int j = 0; j < 8; ++j) ls += __expf(vals[j] - M);
  red[t] = ls; __syncthreads();
  for (int s = 128; s > 0; s >>= 1) {
    if (t < s) red[t] += red[t + s];
    __syncthreads();
  }
  const float inv = 1.f / red[0];
#pragma unroll
  for (int j = 0; j < 8; ++j) w2[(size_t)b * LDIM + t + j * 256] = __expf(vals[j] - M) * inv;
}

// ---------------- o2 (finer grid: 32 rows/block, 1024 blocks) ----------------
__global__ __launch_bounds__(256) void o2_kernel(const float* __restrict__ input,
                                                 const float* __restrict__ w2,
                                                 float* __restrict__ o2) {
  const int b = blockIdx.y, ch = blockIdx.x, t = threadIdx.x;
  __shared__ float sw[32];
  if (t < 32) sw[t] = w2[(size_t)b * LDIM + ch * 32 + t];
  __syncthreads();
  const float* ib = input + ((size_t)b * LDIM + ch * 32) * DDIM;
  float4 acc = {0.f, 0.f, 0.f, 0.f};
  for (int l = 0; l < 32; ++l) {
    const float w = sw[l];
    float4 v = *(const float4*)&ib[(size_t)l * DDIM + t * 4];
    acc.x += w * v.x; acc.y += w * v.y; acc.z += w * v.z; acc.w += w * v.w;
  }
  atomicAdd(&o2[b * DDIM + t * 4 + 0], acc.x);
  atomicAdd(&o2[b * DDIM + t * 4 + 1], acc.y);
  atomicAdd(&o2[b * DDIM + t * 4 + 2], acc.z);
  atomicAdd(&o2[b * DDIM + t * 4 + 3], acc.w);
}

// ---------------- GEMM2: o1 = P @ V, fused vectorized epilogue ----------------
__global__ __launch_bounds__(256, 4) void gemm2_kernel(
    const _Float16* __restrict__ Pm, const _Float16* __restrict__ Vt,
    const float* __restrict__ input, const float* __restrict__ o2,
    float* __restrict__ out) {
  const int id = blockIdx.x;                  // nwg = 2048
  const int wg = (id & 7) * 256 + (id >> 3);
  const int b = wg >> 7, rem = wg & 127, by = rem >> 3, bx = rem & 7;
  const int t = threadIdx.x, lane = t & 63, wid = t >> 6;
  const int wr = wid >> 1, wc = wid & 1;
  __shared__ union SM2 {
    struct { _Float16 a[128 * 64]; _Float16 b[128 * 64]; } ab;
    float c[16 * 132];                        // padded C-panel stage
  } sm;
  const _Float16* Ab = Pm + ((size_t)b * LDIM + by * 128) * MDIM;
  const _Float16* Bb = Vt + ((size_t)b * DDIM + bx * 128) * MDIM;
  f32x4v acc[4][4];
#pragma unroll
  for (int i = 0; i < 4; ++i)
#pragma unroll
    for (int j = 0; j < 4; ++j) acc[i][j] = (f32x4v){0.f, 0.f, 0.f, 0.f};

  for (int ks = 0; ks < MDIM / 64; ++ks) {
    __syncthreads();
    stage128(Ab, Bb, sm.ab.a, sm.ab.b, MDIM, ks * 64, wid, lane);
    __syncthreads();
    compute128(sm.ab.a, sm.ab.b, acc, wr, wc, lane);
  }

  // epilogue: 8 panels of 16 rows x 128 cols, staged f32 in LDS, float4 nt out
  const int cq = (t & 15) * 4;
  const float4 o2a = *(const float4*)&o2[b * DDIM + bx * 128 + cq];
  const float4 o2b = *(const float4*)&o2[b * DDIM + bx * 128 + 64 + cq];
  const int r16 = t >> 4;
  __syncthreads();
#pragma unroll
  for (int pp = 0; pp < 8; ++pp) {
    if (wr == (pp >> 2)) {
      const int pmi = pp & 3;
#pragma unroll
      for (int ni = 0; ni < 4; ++ni)
#pragma unroll
        for (int r = 0; r < 4; ++r)
          sm.c[((lane >> 4) * 4 + r) * 132 + wc * 64 + ni * 16 + (lane & 15)] =
              acc[pmi][ni][r];
    }
    __syncthreads();
    const size_t l = (size_t)by * 128 + pp * 16 + r16;
    const float4 c0 = *(const float4*)&sm.c[r16 * 132 + cq];
    const float4 c1 = *(const float4*)&sm.c[r16 * 132 + 64 + cq];
    const float* ibp = &input[((size_t)b * LDIM + l) * DDIM + bx * 128];
    const float4 i0 = *(const float4*)&ibp[cq];
    const float4 i1 = *(const float4*)&ibp[64 + cq];
    float* ob = &out[((size_t)b * LDIM + l) * (4 * DDIM) + bx * 128];
    nts4(i0, ob + cq);
    nts4(i1, ob + 64 + cq);
    nts4(c0, ob + DDIM + cq);
    nts4(c1, ob + DDIM + 64 + cq);
    nts4(m4(i0, c0), ob + 2 * DDIM + cq);
    nts4(m4(i1, c1), ob + 2 * DDIM + 64 + cq);
    nts4(m4(o2a, c0), ob + 3 * DDIM + cq);
    nts4(m4(o2b, c1), ob + 3 * DDIM + 64 + cq);
    __syncthreads();
  }
}

extern "C" void kernel_launch(void* const* d_in, const int* in_sizes, int n_in,
                              void* d_out, int out_size, void* d_ws, size_t ws_size,
                              hipStream_t stream) {
  (void)in_sizes; (void)n_in; (void)out_size; (void)ws_size;
  const float* input  = (const float*)d_in[0];
  const float* memory = (const float*)d_in[1];
  const int*   mask   = (const int*)d_in[2];
  const float* w_in   = (const float*)d_in[3];
  const float* w_mem  = (const float*)d_in[4];
  const float* scale  = (const float*)d_in[5];
  float* out = (float*)d_out;

  char* p = (char*)d_ws;
  _Float16* Qh = (_Float16*)p; p += (size_t)BDIM * LDIM * DDIM * 2;
  _Float16* Kh = (_Float16*)p; p += (size_t)BDIM * MDIM * DDIM * 2;
  _Float16* Vt = (_Float16*)p; p += (size_t)BDIM * DDIM * MDIM * 2;
  _Float16* Sp = (_Float16*)p; p += (size_t)BDIM * LDIM * MDIM * 2;
  float* idot = (float*)p; p += (size_t)BDIM * LDIM * 4;
  float* mdot = (float*)p; p += (size_t)BDIM * MDIM * 4;
  float* rmax = (float*)p; p += (size_t)BDIM * LDIM * 4;
  float* w2   = (float*)p; p += (size_t)BDIM * LDIM * 4;
  float* o2   = (float*)p; p += (size_t)BDIM * DDIM * 4;

  conv_in<<<dim3(BDIM * LDIM / 4), dim3(256), 0, stream>>>(
      input, w_in, scale, Qh, idot);
  conv_mem<<<dim3(MDIM / 64, BDIM), dim3(256), 0, stream>>>(
      memory, w_mem, Kh, Vt, mdot);
  gemm1_kernel<<<dim3(BDIM * 16 * 16), dim3(256), 0, stream>>>(
      Qh, Kh, idot, mdot, mask, Sp);
  softmax_rows<<<dim3(BDIM * LDIM / 4), dim3(256), 0, stream>>>(Sp, rmax);
  w2a_kernel<<<dim3(BDIM), dim3(256), 0, stream>>>(rmax, w2, o2);
  o2_kernel<<<dim3(LDIM / 32, BDIM), dim3(256), 0, stream>>>(input, w2, o2);
  gemm2_kernel<<<dim3(BDIM * 16 * 8), dim3(256), 0, stream>>>(
      Sp, Vt, input, o2, out);
}

// Round 13
// 554.345 us; speedup vs baseline: 1.0107x; 1.0107x over previous
//
#include <hip/hip_runtime.h>
#include <hip/hip_bf16.h>

// BiAttention: B=16, L=M=2048, D=1024.
//  conv -> tr -> gemm1(S=QK^T+dots,mask) -> softmax_rows -> w2a(+o2 zero) -> o2 -> gemm2(fused epilogue)
// R13 = R8 verbatim (best-measured: 551 us). m97 128^2 2-barrier GEMMs,
// 16x16x32 MFMA, __launch_bounds__(256,4) (4 blocks/CU), GL16 width-16,
// zero-conflict xor swizzle, LDS-staged vectorized epilogues, XCD swizzle,
// nontemporal f32x4 output stores.
// Closed lanes this session: 8-phase schedule (R3/R4/R9), explicit dbuf /
// fine-vmcnt (R4, documented m99/m131 nulls), 32x32 MFMA (R10 swizzle-period
// conflict), f16 input shadow (R11 neutral), tr-fusion + o2 split (R12 neutral).

#define BDIM 16
#define LDIM 2048
#define MDIM 2048
#define DDIM 1024
#define NEGF (-60000.0f)

typedef float    f32x4v __attribute__((ext_vector_type(4)));
typedef _Float16 half8  __attribute__((ext_vector_type(8)));
typedef _Float16 half4  __attribute__((ext_vector_type(4)));

#define GL16(gp, lp)                                                        \
  __builtin_amdgcn_global_load_lds(                                         \
      (const __attribute__((address_space(1))) unsigned int*)(gp),          \
      (__attribute__((address_space(3))) unsigned int*)(lp), 16, 0, 0)

__device__ __forceinline__ float4 m4(const float4 a, const float4 b) {
  return (float4){a.x * b.x, a.y * b.y, a.z * b.z, a.w * b.w};
}
__device__ __forceinline__ void nts4(const float4 v, float* p) {
  f32x4v w = {v.x, v.y, v.z, v.w};
  __builtin_nontemporal_store(w, (f32x4v*)p);
}

// ---------------- conversion + row dots ----------------
__global__ __launch_bounds__(256) void conv_kernel(
    const float* __restrict__ input, const float* __restrict__ memory,
    const float* __restrict__ w_in, const float* __restrict__ w_mem,
    const float* __restrict__ scale,
    _Float16* __restrict__ Qh, _Float16* __restrict__ Kh,
    float* __restrict__ idot, float* __restrict__ mdot) {
  const int t = threadIdx.x, lane = t & 63, wid = t >> 6;
  const size_t row = (size_t)blockIdx.x * 4 + wid;
  const float* ir  = input  + row * DDIM;
  const float* mrp = memory + row * DDIM;
  float di = 0.f, dm = 0.f;
#pragma unroll
  for (int c = 0; c < 4; ++c) {
    const int off = c * 256 + lane * 4;
    float4 sc4 = *(const float4*)&scale[off];
    float4 wi4 = *(const float4*)&w_in[off];
    float4 wm4 = *(const float4*)&w_mem[off];
    float4 v = *(const float4*)&ir[off];
    di += v.x * wi4.x + v.y * wi4.y + v.z * wi4.z + v.w * wi4.w;
    half4 q = { (_Float16)(v.x * sc4.x), (_Float16)(v.y * sc4.y),
                (_Float16)(v.z * sc4.z), (_Float16)(v.w * sc4.w) };
    *(half4*)&Qh[row * DDIM + off] = q;
    float4 u = *(const float4*)&mrp[off];
    dm += u.x * wm4.x + u.y * wm4.y + u.z * wm4.z + u.w * wm4.w;
    half4 k = { (_Float16)u.x, (_Float16)u.y, (_Float16)u.z, (_Float16)u.w };
    *(half4*)&Kh[row * DDIM + off] = k;
  }
#pragma unroll
  for (int o = 1; o < 64; o <<= 1) {
    di += __shfl_xor(di, o, 64);
    dm += __shfl_xor(dm, o, 64);
  }
  if (lane == 0) { idot[row] = di; mdot[row] = dm; }
}

// ---------------- transpose memory (f16) -> Vt[b][d][m] ----------------
__global__ __launch_bounds__(256) void tr_kernel(const _Float16* __restrict__ Kh,
                                                 _Float16* __restrict__ Vt) {
  const int b = blockIdx.z;
  const int d0 = blockIdx.x * 64, m0 = blockIdx.y * 64;
  __shared__ _Float16 sT[64][80];
  const int t = threadIdx.x;
  {
    const int mr = t >> 2, ch = (t & 3) * 16;
    const _Float16* src = Kh + ((size_t)b * MDIM + m0 + mr) * DDIM + d0 + ch;
    *(half8*)&sT[mr][ch]     = *(const half8*)&src[0];
    *(half8*)&sT[mr][ch + 8] = *(const half8*)&src[8];
  }
  __syncthreads();
  {
    const int dr = t >> 2, mc = (t & 3) * 16;
    union { _Float16 h[16]; half8 v[2]; } tmp;
#pragma unroll
    for (int j = 0; j < 16; ++j) tmp.h[j] = sT[mc + j][dr];
    _Float16* dst = Vt + ((size_t)b * DDIM + d0 + dr) * MDIM + m0 + mc;
    *(half8*)&dst[0] = tmp.v[0];
    *(half8*)&dst[8] = tmp.v[1];
  }
}

// ============ m97-style 128^2 GEMM core (R5/R8, proven) ============
__device__ __forceinline__ void stage128(const _Float16* __restrict__ Ab,
                                         const _Float16* __restrict__ Bb,
                                         _Float16* sAb, _Float16* sBb,
                                         int stride, int k0, int wid, int lane) {
  const int rsub = lane >> 3;
  const int sc = ((lane & 7) ^ rsub) * 8;
#pragma unroll
  for (int j = 0; j < 4; ++j) {
    const int r0 = wid * 32 + j * 8;
    const size_t go = (size_t)(r0 + rsub) * stride + k0 + sc;
    GL16(Ab + go, sAb + r0 * 64);
    GL16(Bb + go, sBb + r0 * 64);
  }
}

__device__ __forceinline__ void compute128(const _Float16* sAb, const _Float16* sBb,
                                           f32x4v acc[4][4], int wr, int wc,
                                           int lane) {
  const int l15 = lane & 15;
#pragma unroll
  for (int kk = 0; kk < 2; ++kk) {
    const int colh = ((kk * 4 + (lane >> 4)) ^ (lane & 7)) * 8;
    half8 aF[4], bF[4];
#pragma unroll
    for (int i = 0; i < 4; ++i) {
      aF[i] = *(const half8*)&sAb[(wr * 64 + i * 16 + l15) * 64 + colh];
      bF[i] = *(const half8*)&sBb[(wc * 64 + i * 16 + l15) * 64 + colh];
    }
#pragma unroll
    for (int mi = 0; mi < 4; ++mi)
#pragma unroll
      for (int ni = 0; ni < 4; ++ni)
        acc[mi][ni] = __builtin_amdgcn_mfma_f32_16x16x32_f16(aF[mi], bF[ni],
                                                             acc[mi][ni], 0, 0, 0);
  }
}

// ---------------- GEMM1: S = Q @ K^T + dots, masked ----------------
__global__ __launch_bounds__(256, 4) void gemm1_kernel(
    const _Float16* __restrict__ Qh, const _Float16* __restrict__ Kh,
    const float* __restrict__ idot, const float* __restrict__ mdot,
    const int* __restrict__ mask, _Float16* __restrict__ Sp) {
  const int id = blockIdx.x;                  // nwg = 4096
  const int wg = (id & 7) * 512 + (id >> 3);
  const int b = wg >> 8, rem = wg & 255, by = rem >> 4, bx = rem & 15;
  const int t = threadIdx.x, lane = t & 63, wid = t >> 6;
  const int wr = wid >> 1, wc = wid & 1;
  __shared__ union SM1 {
    struct { _Float16 a[128 * 64]; _Float16 b[128 * 64]; } ab;
    _Float16 s[128 * 140];                     // padded S-tile stage
  } sm;
  __shared__ float s_dl[128], s_dm[128];
  __shared__ int   s_ml[128], s_mm[128];
  if (t < 128) {
    s_dl[t] = idot[b * LDIM + by * 128 + t];
    s_ml[t] = mask[b * LDIM + by * 128 + t];
    s_dm[t] = mdot[b * MDIM + bx * 128 + t];
    s_mm[t] = mask[b * MDIM + bx * 128 + t];
  }
  const _Float16* Ab = Qh + ((size_t)b * LDIM + by * 128) * DDIM;
  const _Float16* Bb = Kh + ((size_t)b * MDIM + bx * 128) * DDIM;
  f32x4v acc[4][4];
#pragma unroll
  for (int i = 0; i < 4; ++i)
#pragma unroll
    for (int j = 0; j < 4; ++j) acc[i][j] = (f32x4v){0.f, 0.f, 0.f, 0.f};

  for (int ks = 0; ks < DDIM / 64; ++ks) {
    __syncthreads();
    stage128(Ab, Bb, sm.ab.a, sm.ab.b, DDIM, ks * 64, wid, lane);
    __syncthreads();
    compute128(sm.ab.a, sm.ab.b, acc, wr, wc, lane);
  }

  // epilogue: stage f16 S-tile in LDS, then half8 row writes
  __syncthreads();
  const int rb = wr * 64, cb = wc * 64;
#pragma unroll
  for (int mi = 0; mi < 4; ++mi)
#pragma unroll
    for (int ni = 0; ni < 4; ++ni)
#pragma unroll
      for (int r = 0; r < 4; ++r) {
        const int lrow = rb + mi * 16 + (lane >> 4) * 4 + r;
        const int lcol = cb + ni * 16 + (lane & 15);
        float s = acc[mi][ni][r] + s_dl[lrow] + s_dm[lcol];
        if ((s_ml[lrow] | s_mm[lcol]) != 0) s = NEGF;
        sm.s[lrow * 140 + lcol] = (_Float16)s;
      }
  __syncthreads();
  const int r16 = t >> 4, c8 = (t & 15) * 8;
#pragma unroll
  for (int rd = 0; rd < 8; ++rd) {
    const int lrow = rd * 16 + r16;
    half8 v = *(const half8*)&sm.s[lrow * 140 + c8];
    *(half8*)&Sp[((size_t)b * LDIM + by * 128 + lrow) * MDIM + bx * 128 + c8] = v;
  }
}

// ---------------- per-row softmax (in place) + rowmax ----------------
__global__ __launch_bounds__(256) void softmax_rows(_Float16* __restrict__ Sp,
                                                    float* __restrict__ rmax) {
  const int t = threadIdx.x, lane = t & 63, wid = t >> 6;
  const size_t row = (size_t)blockIdx.x * 4 + wid;
  _Float16* rp = Sp + row * (size_t)MDIM;
  float s[32];
#pragma unroll
  for (int c = 0; c < 4; ++c) {
    half8 v = *(const half8*)&rp[c * 512 + lane * 8];
#pragma unroll
    for (int j = 0; j < 8; ++j) s[c * 8 + j] = (float)v[j];
  }
  float m = -3.0e38f;
#pragma unroll
  for (int i = 0; i < 32; ++i) m = fmaxf(m, s[i]);
#pragma unroll
  for (int o = 1; o < 64; o <<= 1) m = fmaxf(m, __shfl_xor(m, o, 64));
  float sum = 0.f;
#pragma unroll
  for (int i = 0; i < 32; ++i) { s[i] = __expf(s[i] - m); sum += s[i]; }
#pragma unroll
  for (int o = 1; o < 64; o <<= 1) sum += __shfl_xor(sum, o, 64);
  const float inv = 1.f / sum;
#pragma unroll
  for (int c = 0; c < 4; ++c) {
    half8 v;
#pragma unroll
    for (int j = 0; j < 8; ++j) v[j] = (_Float16)(s[c * 8 + j] * inv);
    *(half8*)&rp[c * 512 + lane * 8] = v;
  }
  if (lane == 0) rmax[row] = m;
}

// ---------------- w2 = softmax_l(rowmax) per batch (+ zero o2) ----------------
__global__ __launch_bounds__(256) void w2a_kernel(const float* __restrict__ rmax,
                                                  float* __restrict__ w2,
                                                  float* __restrict__ o2) {
  const int b = blockIdx.x, t = threadIdx.x;
  ((float4*)(o2 + (size_t)b * DDIM))[t] = (float4){0.f, 0.f, 0.f, 0.f};
  __shared__ float red[256];
  const float* rm = rmax + (size_t)b * LDIM;
  float vals[8]; float lm = -3.0e38f;
#pragma unroll
  for (int j = 0; j < 8; ++j) { vals[j] = rm[t + j * 256]; lm = fmaxf(lm, vals[j]); }
  red[t] = lm; __syncthreads();
  for (int s = 128; s > 0; s >>= 1) {
    if (t < s) red[t] = fmaxf(red[t], red[t + s]);
    __syncthreads();
  }
  const float M = red[0]; __syncthreads();
  float ls = 0.f;
#pragma unroll
  for (int j = 0; j < 8; ++j) ls += __expf(vals[j] - M);
  red[t] = ls; __syncthreads();
  for (int s = 128; s > 0; s >>= 1) {
    if (t < s) red[t] += red[t + s];
    __syncthreads();
  }
  const float inv = 1.f / red[0];
#pragma unroll
  for (int j = 0; j < 8; ++j) w2[(size_t)b * LDIM + t + j * 256] = __expf(vals[j] - M) * inv;
}

// ---------------- o2 ----------------
__global__ __launch_bounds__(256) void o2_kernel(const float* __restrict__ input,
                                                 const float* __restrict__ w2,
                                                 float* __restrict__ o2) {
  const int b = blockIdx.y, ch = blockIdx.x, t = threadIdx.x;
  __shared__ float sw[128];
  if (t < 128) sw[t] = w2[(size_t)b * LDIM + ch * 128 + t];
  __syncthreads();
  const float* ib = input + ((size_t)b * LDIM + ch * 128) * DDIM;
  float4 acc = {0.f, 0.f, 0.f, 0.f};
  for (int l = 0; l < 128; ++l) {
    const float w = sw[l];
    float4 v = *(const float4*)&ib[(size_t)l * DDIM + t * 4];
    acc.x += w * v.x; acc.y += w * v.y; acc.z += w * v.z; acc.w += w * v.w;
  }
  atomicAdd(&o2[b * DDIM + t * 4 + 0], acc.x);
  atomicAdd(&o2[b * DDIM + t * 4 + 1], acc.y);
  atomicAdd(&o2[b * DDIM + t * 4 + 2], acc.z);
  atomicAdd(&o2[b * DDIM + t * 4 + 3], acc.w);
}

// ---------------- GEMM2: o1 = P @ V, fused vectorized epilogue ----------------
__global__ __launch_bounds__(256, 4) void gemm2_kernel(
    const _Float16* __restrict__ Pm, const _Float16* __restrict__ Vt,
    const float* __restrict__ input, const float* __restrict__ o2,
    float* __restrict__ out) {
  const int id = blockIdx.x;                  // nwg = 2048
  const int wg = (id & 7) * 256 + (id >> 3);
  const int b = wg >> 7, rem = wg & 127, by = rem >> 3, bx = rem & 7;
  const int t = threadIdx.x, lane = t & 63, wid = t >> 6;
  const int wr = wid >> 1, wc = wid & 1;
  __shared__ union SM2 {
    struct { _Float16 a[128 * 64]; _Float16 b[128 * 64]; } ab;
    float c[16 * 132];                        // padded C-panel stage
  } sm;
  const _Float16* Ab = Pm + ((size_t)b * LDIM + by * 128) * MDIM;
  const _Float16* Bb = Vt + ((size_t)b * DDIM + bx * 128) * MDIM;
  f32x4v acc[4][4];
#pragma unroll
  for (int i = 0; i < 4; ++i)
#pragma unroll
    for (int j = 0; j < 4; ++j) acc[i][j] = (f32x4v){0.f, 0.f, 0.f, 0.f};

  for (int ks = 0; ks < MDIM / 64; ++ks) {
    __syncthreads();
    stage128(Ab, Bb, sm.ab.a, sm.ab.b, MDIM, ks * 64, wid, lane);
    __syncthreads();
    compute128(sm.ab.a, sm.ab.b, acc, wr, wc, lane);
  }

  // epilogue: 8 panels of 16 rows x 128 cols, staged f32 in LDS, float4 nt out
  const int cq = (t & 15) * 4;
  const float4 o2a = *(const float4*)&o2[b * DDIM + bx * 128 + cq];
  const float4 o2b = *(const float4*)&o2[b * DDIM + bx * 128 + 64 + cq];
  const int r16 = t >> 4;
  __syncthreads();
#pragma unroll
  for (int pp = 0; pp < 8; ++pp) {
    if (wr == (pp >> 2)) {
      const int pmi = pp & 3;
#pragma unroll
      for (int ni = 0; ni < 4; ++ni)
#pragma unroll
        for (int r = 0; r < 4; ++r)
          sm.c[((lane >> 4) * 4 + r) * 132 + wc * 64 + ni * 16 + (lane & 15)] =
              acc[pmi][ni][r];
    }
    __syncthreads();
    const size_t l = (size_t)by * 128 + pp * 16 + r16;
    const float4 c0 = *(const float4*)&sm.c[r16 * 132 + cq];
    const float4 c1 = *(const float4*)&sm.c[r16 * 132 + 64 + cq];
    const float* ibp = &input[((size_t)b * LDIM + l) * DDIM + bx * 128];
    const float4 i0 = *(const float4*)&ibp[cq];
    const float4 i1 = *(const float4*)&ibp[64 + cq];
    float* ob = &out[((size_t)b * LDIM + l) * (4 * DDIM) + bx * 128];
    nts4(i0, ob + cq);
    nts4(i1, ob + 64 + cq);
    nts4(c0, ob + DDIM + cq);
    nts4(c1, ob + DDIM + 64 + cq);
    nts4(m4(i0, c0), ob + 2 * DDIM + cq);
    nts4(m4(i1, c1), ob + 2 * DDIM + 64 + cq);
    nts4(m4(o2a, c0), ob + 3 * DDIM + cq);
    nts4(m4(o2b, c1), ob + 3 * DDIM + 64 + cq);
    __syncthreads();
  }
}

extern "C" void kernel_launch(void* const* d_in, const int* in_sizes, int n_in,
                              void* d_out, int out_size, void* d_ws, size_t ws_size,
                              hipStream_t stream) {
  (void)in_sizes; (void)n_in; (void)out_size; (void)ws_size;
  const float* input  = (const float*)d_in[0];
  const float* memory = (const float*)d_in[1];
  const int*   mask   = (const int*)d_in[2];
  const float* w_in   = (const float*)d_in[3];
  const float* w_mem  = (const float*)d_in[4];
  const float* scale  = (const float*)d_in[5];
  float* out = (float*)d_out;

  char* p = (char*)d_ws;
  _Float16* Qh = (_Float16*)p; p += (size_t)BDIM * LDIM * DDIM * 2;
  _Float16* Kh = (_Float16*)p; p += (size_t)BDIM * MDIM * DDIM * 2;
  _Float16* Vt = (_Float16*)p; p += (size_t)BDIM * DDIM * MDIM * 2;
  _Float16* Sp = (_Float16*)p; p += (size_t)BDIM * LDIM * MDIM * 2;
  float* idot = (float*)p; p += (size_t)BDIM * LDIM * 4;
  float* mdot = (float*)p; p += (size_t)BDIM * MDIM * 4;
  float* rmax = (float*)p; p += (size_t)BDIM * LDIM * 4;
  float* w2   = (float*)p; p += (size_t)BDIM * LDIM * 4;
  float* o2   = (float*)p; p += (size_t)BDIM * DDIM * 4;

  conv_kernel<<<dim3(BDIM * LDIM / 4), dim3(256), 0, stream>>>(
      input, memory, w_in, w_mem, scale, Qh, Kh, idot, mdot);
  tr_kernel<<<dim3(DDIM / 64, MDIM / 64, BDIM), dim3(256), 0, stream>>>(Kh, Vt);
  gemm1_kernel<<<dim3(BDIM * 16 * 16), dim3(256), 0, stream>>>(
      Qh, Kh, idot, mdot, mask, Sp);
  softmax_rows<<<dim3(BDIM * LDIM / 4), dim3(256), 0, stream>>>(Sp, rmax);
  w2a_kernel<<<dim3(BDIM), dim3(256), 0, stream>>>(rmax, w2, o2);
  o2_kernel<<<dim3(LDIM / 128, BDIM), dim3(256), 0, stream>>>(input, w2, o2);
  gemm2_kernel<<<dim3(BDIM * 16 * 8), dim3(256), 0, stream>>>(
      Sp, Vt, input, o2, out);
}